// Round 8
// baseline (802.986 us; speedup 1.0000x reference)
//
#include <hip/hip_runtime.h>
#include <stdint.h>

#define GRAPHS 4096
#define NPG 18
#define EPERG 306
#define FIN 1536
#define BN_EPS 1e-5f
#define SLOPE 0.01f

using short8  = __attribute__((ext_vector_type(8))) short;
using ushort8 = __attribute__((ext_vector_type(8))) unsigned short;
using f32x4   = __attribute__((ext_vector_type(4))) float;

__device__ __forceinline__ unsigned short f2bf(float f) {
  unsigned u = __builtin_bit_cast(unsigned, f);
  u += 0x7fffu + ((u >> 16) & 1u);   // RNE to bf16 (inputs are finite)
  return (unsigned short)(u >> 16);
}

__device__ __forceinline__ short8 pack_bf16(const float4& a0, const float4& a1) {
  short8 af;
  af[0] = (short)f2bf(a0.x); af[1] = (short)f2bf(a0.y);
  af[2] = (short)f2bf(a0.z); af[3] = (short)f2bf(a0.w);
  af[4] = (short)f2bf(a1.x); af[5] = (short)f2bf(a1.y);
  af[6] = (short)f2bf(a1.z); af[7] = (short)f2bf(a1.w);
  return af;
}

// same-wave LDS write->read ordering (all rest-phase LDS is wave-private)
__device__ __forceinline__ void wave_fence() {
  asm volatile("s_waitcnt lgkmcnt(0)" ::: "memory");
}

#define REP18(M) M(0) M(1) M(2) M(3) M(4) M(5) M(6) M(7) M(8) M(9) M(10) M(11) M(12) M(13) M(14) M(15) M(16) M(17)
#define REP18B(M,s) M(0,s) M(1,s) M(2,s) M(3,s) M(4,s) M(5,s) M(6,s) M(7,s) M(8,s) M(9,s) M(10,s) M(11,s) M(12,s) M(13,s) M(14,s) M(15,s) M(16,s) M(17,s)

// ---------------------------------------------------------------------------
// Prep (unchanged, proven):
//  blocks 0-23 : repack W1 into bf16 B-frag order for mfma_f32_16x16x32_bf16
//                frag[ks(48)][nt(2)][lane(64)][8], n=nt*16+(lane&15),
//                k=ks*32+(lane>>4)*8+j
//  block 24    : fold bias+BN into per-channel alpha/beta
// ---------------------------------------------------------------------------
__global__ void prep_kernel(const float* __restrict__ W1,
    const float* __restrict__ b1, const float* __restrict__ g1,
    const float* __restrict__ be1, const float* __restrict__ rm1, const float* __restrict__ rv1,
    const float* __restrict__ b2, const float* __restrict__ g2,
    const float* __restrict__ be2, const float* __restrict__ rm2, const float* __restrict__ rv2,
    const float* __restrict__ b3, const float* __restrict__ g3,
    const float* __restrict__ be3, const float* __restrict__ rm3, const float* __restrict__ rv3,
    unsigned short* __restrict__ w1frag, float* __restrict__ ab) {
  const int tid = threadIdx.x;
  if (blockIdx.x < 24) {
    int slot = blockIdx.x * 256 + tid;            // [0, 6144)
    int L  = slot & 63;
    int nt = (slot >> 6) & 1;
    int ks = slot >> 7;                           // [0, 48)
    int n  = nt * 16 + (L & 15);
    int kb = ks * 32 + ((L >> 4) << 3);
    ushort8 v;
#pragma unroll
    for (int j = 0; j < 8; ++j) v[j] = f2bf(W1[(kb + j) * 32 + n]);
    *((ushort8*)w1frag + slot) = v;
  } else {
    // ab layout: a1[0:32] b1[32:64] a2[64:128] b2[128:192] a3[192:320] b3[320:448]
    if (tid < 32) {
      float a = g1[tid] * rsqrtf(rv1[tid] + BN_EPS);
      ab[tid] = a; ab[32 + tid] = (b1[tid] - rm1[tid]) * a + be1[tid];
    }
    if (tid < 64) {
      float a = g2[tid] * rsqrtf(rv2[tid] + BN_EPS);
      ab[64 + tid] = a; ab[128 + tid] = (b2[tid] - rm2[tid]) * a + be2[tid];
    }
    if (tid < 128) {
      float a = g3[tid] * rsqrtf(rv3[tid] + BN_EPS);
      ab[192 + tid] = a; ab[320 + tid] = (b3[tid] - rm3[tid]) * a + be3[tid];
    }
  }
}

// ---------------------------------------------------------------------------
// Kernel A: pure streaming GEMM  P1 = X (73728x1536) @ W1 (1536x32).
// 4608 16-row M-tiles, one wave each. ZERO LDS, ZERO barriers -> high
// occupancy (launch_bounds caps VGPR at 128 = 4 waves/SIMD), deep register
// pipeline (unroll 6), HBM stream never waits on anything else.
// ---------------------------------------------------------------------------
__global__ __launch_bounds__(256, 4) void l1_stream(
    const float* __restrict__ x, const unsigned short* __restrict__ w1frag,
    float* __restrict__ p1) {
  const int lane = threadIdx.x & 63;
  const int wv   = threadIdx.x >> 6;
  const int t    = blockIdx.x * 4 + wv;           // [0, 4608)
  const int arow = lane & 15;                     // A row / C col
  const int akg  = lane >> 4;                     // k-group (0..3)
  const short8* __restrict__ wf = (const short8*)w1frag + lane;
  const float* __restrict__ xr = x + (size_t)(t * 16 + arow) * FIN + (akg << 3);

  f32x4 acc0 = {0.f, 0.f, 0.f, 0.f};
  f32x4 acc1 = {0.f, 0.f, 0.f, 0.f};
#pragma unroll 6
  for (int ks = 0; ks < 48; ++ks) {
    float4 a0 = *(const float4*)(xr + ks * 32);
    float4 a1 = *(const float4*)(xr + ks * 32 + 4);
    short8 af = pack_bf16(a0, a1);
    acc0 = __builtin_amdgcn_mfma_f32_16x16x32_bf16(af, wf[(ks * 2 + 0) * 64], acc0, 0, 0, 0);
    acc1 = __builtin_amdgcn_mfma_f32_16x16x32_bf16(af, wf[(ks * 2 + 1) * 64], acc1, 0, 0, 0);
  }
  // C layout: col = lane&15, row = (lane>>4)*4 + q
  float* p = p1 + (size_t)(t * 16 + (akg << 2)) * 32 + arow;
#pragma unroll
  for (int q = 0; q < 4; ++q) {
    p[q * 32]      = acc0[q];
    p[q * 32 + 16] = acc1[q];
  }
}

// ---------------------------------------------------------------------------
// Kernel B: rest of the GCN, one WAVE per graph (no __syncthreads at all).
// Column-per-lane pipeline: H1/G2/H2/G3 in named registers; An@H aggregations
// are 324 static FMAs vs LDS-broadcast An (no LDS traffic for H). Only the
// cross-column matmuls stage G2/G3 in a small wave-private LDS buffer and use
// R7's proven 18-static-accumulator + weight-prefetch pattern (no spills).
// ~30 KB LDS/block -> ~5 blocks/CU -> latency well hidden.
// FMA orders identical to R7 -> bit-identical results.
// ---------------------------------------------------------------------------
__global__ __launch_bounds__(256, 4) void gcn_rest(
    const float* __restrict__ ew, const float* __restrict__ p1,
    const float* __restrict__ ab,
    const float* __restrict__ W2, const float* __restrict__ W3,
    float* __restrict__ pooled) {
  const int lane = threadIdx.x & 63;
  const int wv   = threadIdx.x >> 6;
  const int g    = blockIdx.x * 4 + wv;           // [0, 4096)

  __shared__ float ews[4][308];
  __shared__ float dinv[4][18];
  __shared__ float Ans[4][18][19];
  __shared__ __align__(16) float Gs[4][18][68];   // wave-private G2 (32c) / G3 (64c)

  float* ew_w = ews[wv];
  for (int i = lane; i < EPERG; i += 64) ew_w[i] = ew[(size_t)g * EPERG + i];
  wave_fence();

  // degrees (self-loop weight 1)
  if (lane < NPG) {
    float deg = 1.0f;
#pragma unroll
    for (int k = 0; k < 17; ++k) {
      int s = k + (k >= lane);
      deg += ew_w[s * 17 + (lane - (lane > s ? 1 : 0))];
    }
    dinv[wv][lane] = rsqrtf(deg);
  }
  wave_fence();

  // normalized adjacency An[d][s]
  for (int o = lane; o < NPG * NPG; o += 64) {
    int d = o / NPG, s = o - d * NPG;
    float v;
    if (d == s) v = dinv[wv][d] * dinv[wv][d];
    else        v = dinv[wv][s] * ew_w[s * 17 + (d - (d > s ? 1 : 0))] * dinv[wv][d];
    Ans[wv][d][s] = v;
  }
  wave_fence();

  const float* Ap = &Ans[wv][0][0];               // Ap[d*19+s], broadcast reads
  float* Gw = &Gs[wv][0][0];                      // row stride 68
  const int cc32 = lane & 31;

  // ---- L1: t_d = sum_s An[d][s] * P1[g][s][cc32]; bn1+lrelu -> h1 in t regs
#define DECLT(i) float t##i = 0.f;
  REP18(DECLT)
#undef DECLT
  {
    const float* P1g = p1 + (size_t)g * 576 + cc32;
    for (int s = 0; s < 18; ++s) {
      float pv = P1g[s * 32];
#define L1F(i) t##i = fmaf(Ap[i * 19 + s], pv, t##i);
      REP18(L1F)
#undef L1F
    }
    const float a1 = ab[cc32], b1v = ab[32 + cc32];
#define BN1(i) { float v = fmaf(t##i, a1, b1v); t##i = v >= 0.f ? v : SLOPE * v; }
    REP18(BN1)
#undef BN1
  }

  // ---- G2_d = sum_s An[d][s] * h1_s  (register-to-register, An broadcast)
#define DECLG(i) float g##i = 0.f;
  REP18(DECLG)
#undef DECLG
#define AGGD(d, s) g##d = fmaf(Ap[d * 19 + s], t##s, g##d);
#define AGGS(s) REP18B(AGGD, s)
  REP18(AGGS)
  // (AGGD/AGGS reused below for G3 — same formula)

  if (lane < 32) {
#define STG2(i) Gw[i * 68 + cc32] = g##i;
    REP18(STG2)
#undef STG2
  }
  wave_fence();

  // ---- L2 mm: h2 = lrelu(bn2(G2 @ W2)) -> t regs (18 static accs, prefetch)
  {
    const float a2 = ab[64 + lane], b2v = ab[128 + lane];
#define Z(i) g##i = 0.f;
    REP18(Z)
#undef Z
    float w0 = W2[0 * 64 + lane], w1 = W2[1 * 64 + lane];
    float w2 = W2[2 * 64 + lane], w3 = W2[3 * 64 + lane];
    for (int k4 = 0; k4 < 8; ++k4) {
      float n0 = 0.f, n1 = 0.f, n2 = 0.f, n3 = 0.f;
      if (k4 < 7) {
        n0 = W2[(k4 * 4 + 4) * 64 + lane]; n1 = W2[(k4 * 4 + 5) * 64 + lane];
        n2 = W2[(k4 * 4 + 6) * 64 + lane]; n3 = W2[(k4 * 4 + 7) * 64 + lane];
      }
#define L2R(i) { f32x4 q = *(const f32x4*)(Gw + i * 68 + k4 * 4); \
      g##i = fmaf(q[0], w0, fmaf(q[1], w1, fmaf(q[2], w2, fmaf(q[3], w3, g##i)))); }
      REP18(L2R)
#undef L2R
      w0 = n0; w1 = n1; w2 = n2; w3 = n3;
    }
#define BN2(i) { float v = fmaf(g##i, a2, b2v); t##i = v >= 0.f ? v : SLOPE * v; }
    REP18(BN2)
#undef BN2
  }

  // ---- G3_d = sum_s An[d][s] * h2_s  (same macro, t now holds h2)
#define Z(i) g##i = 0.f;
  REP18(Z)
#undef Z
  REP18(AGGS)
#undef AGGS
#undef AGGD

#define STG3(i) Gw[i * 68 + lane] = g##i;
  REP18(STG3)
#undef STG3
  wave_fence();

  // ---- L3 mm + bn3 + lrelu + fused mean pool (t regs reused as accs)
  float pool0 = 0.f, pool1 = 0.f;
#pragma unroll 1
  for (int h = 0; h < 2; ++h) {
    const int cc = (h << 6) + lane;
    const float a3 = ab[192 + cc], b3v = ab[320 + cc];
#define Z3(i) t##i = 0.f;
    REP18(Z3)
#undef Z3
    float w0 = W3[0 * 128 + cc], w1 = W3[1 * 128 + cc];
    float w2 = W3[2 * 128 + cc], w3 = W3[3 * 128 + cc];
    for (int k4 = 0; k4 < 16; ++k4) {
      float n0 = 0.f, n1 = 0.f, n2 = 0.f, n3 = 0.f;
      if (k4 < 15) {
        n0 = W3[(k4 * 4 + 4) * 128 + cc]; n1 = W3[(k4 * 4 + 5) * 128 + cc];
        n2 = W3[(k4 * 4 + 6) * 128 + cc]; n3 = W3[(k4 * 4 + 7) * 128 + cc];
      }
#define L3R(i) { f32x4 q = *(const f32x4*)(Gw + i * 68 + k4 * 4); \
      t##i = fmaf(q[0], w0, fmaf(q[1], w1, fmaf(q[2], w2, fmaf(q[3], w3, t##i)))); }
      REP18(L3R)
#undef L3R
      w0 = n0; w1 = n1; w2 = n2; w3 = n3;
    }
    float pr = 0.f;
#define PL(i) { float v = fmaf(t##i, a3, b3v); pr += (v >= 0.f ? v : SLOPE * v); }
    REP18(PL)
#undef PL
    if (h == 0) pool0 = pr * (1.0f / 18.0f); else pool1 = pr * (1.0f / 18.0f);
  }
  pooled[(size_t)g * 128 + lane]      = pool0;
  pooled[(size_t)g * 128 + 64 + lane] = pool1;
}

// ---------------------------------------------------------------------------
// Head kernel (unchanged from R7, proven): 1024 blocks x 4 waves, one graph
// per wave, all weights staged in LDS -> broadcast reads, no serial global
// load chain.
// ---------------------------------------------------------------------------
__global__ __launch_bounds__(256) void head_kernel(
    const float* __restrict__ pooled,
    const float* __restrict__ fW1, const float* __restrict__ fb1,
    const float* __restrict__ fW2, const float* __restrict__ fb2,
    const float* __restrict__ fW3, const float* __restrict__ fb3,
    const float* __restrict__ fW4, const float* __restrict__ fb4,
    float* __restrict__ out) {
  const int tid  = threadIdx.x;
  const int lane = tid & 63;
  const int wv   = tid >> 6;

  __shared__ __align__(16) float w1s[128 * 64];   // 32 KB
  __shared__ __align__(16) float w2s[64 * 32];    // 8 KB
  __shared__ __align__(16) float w3s[32 * 16];    // 2 KB
  __shared__ float w4s[16];

  for (int i = tid; i < 128 * 64; i += 256) w1s[i] = fW1[i];
  for (int i = tid; i < 64 * 32; i += 256)  w2s[i] = fW2[i];
  for (int i = tid; i < 32 * 16; i += 256)  w3s[i] = fW3[i];
  if (tid < 16) w4s[tid] = fW4[tid];
  __syncthreads();

  const int g = (blockIdx.x << 2) + wv;
  const float p0 = pooled[(size_t)g * 128 + lane];
  const float p1 = pooled[(size_t)g * 128 + 64 + lane];

  float s1 = fb1[lane];
#pragma unroll
  for (int k = 0; k < 64; ++k) s1 = fmaf(__shfl(p0, k), w1s[k * 64 + lane], s1);
#pragma unroll
  for (int k = 0; k < 64; ++k) s1 = fmaf(__shfl(p1, k), w1s[(64 + k) * 64 + lane], s1);
  s1 = s1 >= 0.f ? s1 : SLOPE * s1;

  float s2 = fb2[lane & 31];
#pragma unroll
  for (int k = 0; k < 64; ++k) s2 = fmaf(__shfl(s1, k), w2s[k * 32 + (lane & 31)], s2);
  s2 = s2 >= 0.f ? s2 : SLOPE * s2;

  float s3 = fb3[lane & 15];
#pragma unroll
  for (int k = 0; k < 32; ++k) s3 = fmaf(__shfl(s2, k), w3s[k * 16 + (lane & 15)], s3);
  s3 = s3 >= 0.f ? s3 : SLOPE * s3;

  float s4 = fb4[0];
#pragma unroll
  for (int k = 0; k < 16; ++k) s4 = fmaf(__shfl(s3, k), w4s[k], s4);
  if (lane == 0) out[g] = s4;
}

extern "C" void kernel_launch(void* const* d_in, const int* in_sizes, int n_in,
                              void* d_out, int out_size, void* d_ws, size_t ws_size,
                              hipStream_t stream) {
  const float* x   = (const float*)d_in[0];
  // d_in[1] = edge_index (structure known analytically), d_in[3] = batch: unused
  const float* ew  = (const float*)d_in[2];
  const float* W1  = (const float*)d_in[4];
  const float* b1  = (const float*)d_in[5];
  const float* g1  = (const float*)d_in[6];
  const float* be1 = (const float*)d_in[7];
  const float* rm1 = (const float*)d_in[8];
  const float* rv1 = (const float*)d_in[9];
  const float* W2  = (const float*)d_in[10];
  const float* b2  = (const float*)d_in[11];
  const float* g2  = (const float*)d_in[12];
  const float* be2 = (const float*)d_in[13];
  const float* rm2 = (const float*)d_in[14];
  const float* rv2 = (const float*)d_in[15];
  const float* W3  = (const float*)d_in[16];
  const float* b3  = (const float*)d_in[17];
  const float* g3  = (const float*)d_in[18];
  const float* be3 = (const float*)d_in[19];
  const float* rm3 = (const float*)d_in[20];
  const float* rv3 = (const float*)d_in[21];
  const float* fW1 = (const float*)d_in[22];
  const float* fb1 = (const float*)d_in[23];
  const float* fW2 = (const float*)d_in[24];
  const float* fb2 = (const float*)d_in[25];
  const float* fW3 = (const float*)d_in[26];
  const float* fb3 = (const float*)d_in[27];
  const float* fW4 = (const float*)d_in[28];
  const float* fb4 = (const float*)d_in[29];

  // workspace layout (aligned offsets):
  unsigned short* w1frag = (unsigned short*)d_ws;            //       0,   98304 B
  float* ab     = (float*)((char*)d_ws + 98304);             //   98304,    1792 B
  float* pooled = (float*)((char*)d_ws + 102400);            //  102400, 2097152 B
  float* p1     = (float*)((char*)d_ws + 2199552);           // 2199552, 9437184 B

  prep_kernel<<<25, 256, 0, stream>>>(W1, b1, g1, be1, rm1, rv1,
                                      b2, g2, be2, rm2, rv2,
                                      b3, g3, be3, rm3, rv3,
                                      w1frag, ab);
  l1_stream<<<1152, 256, 0, stream>>>(x, w1frag, p1);
  gcn_rest<<<1024, 256, 0, stream>>>(ew, p1, ab, W2, W3, pooled);
  head_kernel<<<1024, 256, 0, stream>>>(pooled, fW1, fb1, fW2, fb2,
                                        fW3, fb3, fW4, fb4, (float*)d_out);
}

// Round 9
// 718.560 us; speedup vs baseline: 1.1175x; 1.1175x over previous
//
#include <hip/hip_runtime.h>
#include <stdint.h>

#define GRAPHS 4096
#define NPG 18
#define EPERG 306
#define FIN 1536
#define BN_EPS 1e-5f
#define SLOPE 0.01f

using short8  = __attribute__((ext_vector_type(8))) short;
using ushort8 = __attribute__((ext_vector_type(8))) unsigned short;
using f32x4   = __attribute__((ext_vector_type(4))) float;
using f32x16  = __attribute__((ext_vector_type(16))) float;

__device__ __forceinline__ unsigned short f2bf(float f) {
  unsigned u = __builtin_bit_cast(unsigned, f);
  u += 0x7fffu + ((u >> 16) & 1u);   // RNE to bf16 (inputs are finite)
  return (unsigned short)(u >> 16);
}

// ---------------------------------------------------------------------------
// Prep (R3-proven):
//  blocks 0-23 : repack W1 into bf16 B-frag order for mfma_f32_32x32x16_bf16:
//                frag[kstep(96)][lane(64)][8], n=lane&31, k=ks*16+(lane>>5)*8+j
//  block 24    : fold bias+BN into per-channel alpha/beta
// ---------------------------------------------------------------------------
__global__ void prep_kernel(const float* __restrict__ W1,
    const float* __restrict__ b1, const float* __restrict__ g1,
    const float* __restrict__ be1, const float* __restrict__ rm1, const float* __restrict__ rv1,
    const float* __restrict__ b2, const float* __restrict__ g2,
    const float* __restrict__ be2, const float* __restrict__ rm2, const float* __restrict__ rv2,
    const float* __restrict__ b3, const float* __restrict__ g3,
    const float* __restrict__ be3, const float* __restrict__ rm3, const float* __restrict__ rv3,
    unsigned short* __restrict__ w1frag, float* __restrict__ ab) {
  const int tid = threadIdx.x;
  if (blockIdx.x < 24) {
    int slot = blockIdx.x * 256 + tid;            // [0, 6144)
    int L  = slot & 63;
    int ks = slot >> 6;                           // [0, 96)
    int n  = L & 31;
    int kb = ks * 16 + ((L >> 5) << 3);
    ushort8 v;
#pragma unroll
    for (int j = 0; j < 8; ++j) v[j] = f2bf(W1[(kb + j) * 32 + n]);
    *((ushort8*)w1frag + slot) = v;
  } else {
    // ab layout: a1[0:32] b1[32:64] a2[64:128] b2[128:192] a3[192:320] b3[320:448]
    if (tid < 32) {
      float a = g1[tid] * rsqrtf(rv1[tid] + BN_EPS);
      ab[tid] = a; ab[32 + tid] = (b1[tid] - rm1[tid]) * a + be1[tid];
    }
    if (tid < 64) {
      float a = g2[tid] * rsqrtf(rv2[tid] + BN_EPS);
      ab[64 + tid] = a; ab[128 + tid] = (b2[tid] - rm2[tid]) * a + be2[tid];
    }
    if (tid < 128) {
      float a = g3[tid] * rsqrtf(rv3[tid] + BN_EPS);
      ab[192 + tid] = a; ab[320 + tid] = (b3[tid] - rm3[tid]) * a + be3[tid];
    }
  }
}

// ---------------------------------------------------------------------------
// Fused kernel (R3-proven, 709 us total): one block (256 thr = 4 waves) per
// graph. Phase 1: layer-1 GEMM via ONE 32x32x16 bf16 MFMA tile, K split 4
// ways across waves, register-streamed loads, no barriers in the stream loop.
// Phase 2: rest with column-per-thread weight access (coalesced, 2x reuse).
// CHANGE vs R3: MLP head removed (it was a ~240-step serial global-load
// chain on a near-idle tail) — we write pooled[g][128] and run the head in
// its own LDS-staged kernel (R7-proven component, bit-identical order).
// ---------------------------------------------------------------------------
__global__ __launch_bounds__(256, 4) void gcn_fused(
    const float* __restrict__ x, const float* __restrict__ ew,
    const unsigned short* __restrict__ w1frag, const float* __restrict__ ab,
    const float* __restrict__ W2, const float* __restrict__ W3,
    float* __restrict__ pooledg) {
  const int g    = blockIdx.x;
  const int tid  = threadIdx.x;
  const int lane = tid & 63;
  const int wv   = tid >> 6;

  __shared__ float ew_s[EPERG];
  __shared__ float dinv_s[NPG];
  __shared__ float An[NPG][NPG + 1];                 // An[dst][src]
  __shared__ __align__(16) float Pb[NPG][132];
  __shared__ __align__(16) float Hb[NPG][132];       // also: K-partial buffer

  // ---- stage edge weights (consumed after the phase-1 barrier) -------------
  for (int i = tid; i < EPERG; i += 256) ew_s[i] = ew[g * EPERG + i];

  // ---- phase 1: layer-1 MFMA, K-split across waves -------------------------
  const int r  = lane & 31;                 // A-row / C-col index
  const int kg = lane >> 5;                 // k-group within 16-wide k-step
  const bool valid = (r < NPG);
  f32x16 acc;
#pragma unroll
  for (int q = 0; q < 16; ++q) acc[q] = 0.f;

  const float* __restrict__ xr =
      x + (size_t)g * NPG * FIN + (size_t)r * FIN + (kg << 3);
  const short8* __restrict__ wf = (const short8*)w1frag + lane;

#pragma unroll 2
  for (int ks = 0; ks < 24; ++ks) {
    const int kidx = wv * 24 + ks;          // global k-step [0,96)
    float4 a0 = {0.f, 0.f, 0.f, 0.f}, a1 = {0.f, 0.f, 0.f, 0.f};
    if (valid) {
      a0 = *(const float4*)(xr + kidx * 16);
      a1 = *(const float4*)(xr + kidx * 16 + 4);
    }
    short8 af;
    af[0] = (short)f2bf(a0.x); af[1] = (short)f2bf(a0.y);
    af[2] = (short)f2bf(a0.z); af[3] = (short)f2bf(a0.w);
    af[4] = (short)f2bf(a1.x); af[5] = (short)f2bf(a1.y);
    af[6] = (short)f2bf(a1.z); af[7] = (short)f2bf(a1.w);
    short8 bf = wf[(size_t)kidx * 64];
    acc = __builtin_amdgcn_mfma_f32_32x32x16_bf16(af, bf, acc, 0, 0, 0);
  }

  // C layout (32x32): col = lane&31, row = (q&3) + 8*(q>>2) + 4*(lane>>5)
  float* HbF = &Hb[0][0];                   // 4 x 576 partial buffer
#pragma unroll
  for (int q = 0; q < 16; ++q) {
    int rr = (q & 3) + ((q >> 2) << 3) + (kg << 2);
    if (rr < NPG) HbF[wv * 576 + rr * 32 + r] = acc[q];
  }
  __syncthreads();

  // ---- degrees (self-loop weight 1) + reduce K-partials → Pb ---------------
  if (tid < NPG) {
    float deg = 1.0f;
#pragma unroll
    for (int j = 0; j < 17; ++j) {
      int s = j + (j >= tid);
      deg += ew_s[s * 17 + (tid - (tid > s ? 1 : 0))];
    }
    dinv_s[tid] = rsqrtf(deg);
  }
  for (int o = tid; o < NPG * 32; o += 256) {
    Pb[o >> 5][o & 31] = HbF[o] + HbF[576 + o] + HbF[1152 + o] + HbF[1728 + o];
  }
  __syncthreads();

  // ---- dense normalized adjacency (18x18) ----------------------------------
  for (int o = tid; o < NPG * NPG; o += 256) {
    int d = o / NPG, s = o - d * NPG;
    float v;
    if (d == s) v = dinv_s[d] * dinv_s[d];
    else        v = dinv_s[s] * ew_s[s * 17 + (d - (d > s ? 1 : 0))] * dinv_s[d];
    An[d][s] = v;
  }
  __syncthreads();

  // ---- layer-1: H1 = lrelu(bn1(An @ P1)) → Hb[:, :32] ----------------------
  for (int o = tid; o < NPG * 32; o += 256) {
    int d = o >> 5, cc = o & 31;
    float s = 0.f;
#pragma unroll
    for (int ss = 0; ss < NPG; ++ss) s = fmaf(An[d][ss], Pb[ss][cc], s);
    float v = fmaf(s, ab[cc], ab[32 + cc]);
    Hb[d][cc] = v >= 0.f ? v : SLOPE * v;
  }
  __syncthreads();

  // ---- layer-2: G2 = An @ H1 → Pb[:, :32] ----------------------------------
  for (int o = tid; o < NPG * 32; o += 256) {
    int d = o >> 5, cc = o & 31;
    float s = 0.f;
#pragma unroll
    for (int ss = 0; ss < NPG; ++ss) s = fmaf(An[d][ss], Hb[ss][cc], s);
    Pb[d][cc] = s;
  }
  __syncthreads();

  // ---- layer-2 mm: H2 = lrelu(bn2(G2 @ W2)) → Hb[:, :64] -------------------
  // column-per-thread: cc = tid&63 (wave-consecutive), rows r = rg + 4i.
  {
    const int cc = tid & 63;
    const int rg = tid >> 6;                // == wave id (uniform per wave)
    float a2[5] = {0.f, 0.f, 0.f, 0.f, 0.f};
#pragma unroll
    for (int k4 = 0; k4 < 8; ++k4) {
      float w0 = W2[(k4 * 4 + 0) * 64 + cc];
      float w1 = W2[(k4 * 4 + 1) * 64 + cc];
      float w2 = W2[(k4 * 4 + 2) * 64 + cc];
      float w3 = W2[(k4 * 4 + 3) * 64 + cc];
#pragma unroll
      for (int i = 0; i < 5; ++i) {
        int rr = rg + 4 * i;
        if (rr < NPG) {
          float4 a = *(const float4*)(&Pb[rr][k4 * 4]);   // LDS broadcast
          a2[i] = fmaf(a.x, w0, fmaf(a.y, w1, fmaf(a.z, w2, fmaf(a.w, w3, a2[i]))));
        }
      }
    }
#pragma unroll
    for (int i = 0; i < 5; ++i) {
      int rr = rg + 4 * i;
      if (rr < NPG) {
        float v = fmaf(a2[i], ab[64 + cc], ab[128 + cc]);
        Hb[rr][cc] = v >= 0.f ? v : SLOPE * v;
      }
    }
  }
  __syncthreads();

  // ---- layer-3: G3 = An @ H2 → Pb[:, :64] ----------------------------------
  for (int o = tid; o < NPG * 64; o += 256) {
    int d = o >> 6, cc = o & 63;
    float s = 0.f;
#pragma unroll
    for (int ss = 0; ss < NPG; ++ss) s = fmaf(An[d][ss], Hb[ss][cc], s);
    Pb[d][cc] = s;
  }
  __syncthreads();

  // ---- layer-3 mm: H3 = lrelu(bn3(G3 @ W3)) → Hb[:, :128] ------------------
  // column-per-thread: cc = tid&127, rows r = rg + 2i (9 rows each).
  {
    const int cc = tid & 127;
    const int rg = tid >> 7;                // uniform per wave
    float a3[9];
#pragma unroll
    for (int i = 0; i < 9; ++i) a3[i] = 0.f;
#pragma unroll
    for (int k4 = 0; k4 < 16; ++k4) {
      float w0 = W3[(k4 * 4 + 0) * 128 + cc];
      float w1 = W3[(k4 * 4 + 1) * 128 + cc];
      float w2 = W3[(k4 * 4 + 2) * 128 + cc];
      float w3 = W3[(k4 * 4 + 3) * 128 + cc];
#pragma unroll
      for (int i = 0; i < 9; ++i) {
        float4 a = *(const float4*)(&Pb[rg + 2 * i][k4 * 4]);  // LDS broadcast
        a3[i] = fmaf(a.x, w0, fmaf(a.y, w1, fmaf(a.z, w2, fmaf(a.w, w3, a3[i]))));
      }
    }
#pragma unroll
    for (int i = 0; i < 9; ++i) {
      int rr = rg + 2 * i;
      float v = fmaf(a3[i], ab[192 + cc], ab[320 + cc]);
      Hb[rr][cc] = v >= 0.f ? v : SLOPE * v;
    }
  }
  __syncthreads();

  // ---- mean pool → global pooled row (coalesced); head runs separately -----
  if (tid < 128) {
    float s = 0.f;
#pragma unroll
    for (int d = 0; d < NPG; ++d) s += Hb[d][tid];
    pooledg[(size_t)g * 128 + tid] = s * (1.0f / 18.0f);
  }
}

// ---------------------------------------------------------------------------
// Head kernel (R7-proven, bit-identical accumulation order): 1024 blocks x 4
// waves, one graph per wave, weights staged in LDS -> broadcast reads, no
// serial global-load chain.
// ---------------------------------------------------------------------------
__global__ __launch_bounds__(256) void head_kernel(
    const float* __restrict__ pooled,
    const float* __restrict__ fW1, const float* __restrict__ fb1,
    const float* __restrict__ fW2, const float* __restrict__ fb2,
    const float* __restrict__ fW3, const float* __restrict__ fb3,
    const float* __restrict__ fW4, const float* __restrict__ fb4,
    float* __restrict__ out) {
  const int tid  = threadIdx.x;
  const int lane = tid & 63;
  const int wv   = tid >> 6;

  __shared__ __align__(16) float w1s[128 * 64];   // 32 KB
  __shared__ __align__(16) float w2s[64 * 32];    // 8 KB
  __shared__ __align__(16) float w3s[32 * 16];    // 2 KB
  __shared__ float w4s[16];

  for (int i = tid; i < 128 * 64; i += 256) w1s[i] = fW1[i];
  for (int i = tid; i < 64 * 32; i += 256)  w2s[i] = fW2[i];
  for (int i = tid; i < 32 * 16; i += 256)  w3s[i] = fW3[i];
  if (tid < 16) w4s[tid] = fW4[tid];
  __syncthreads();

  const int g = (blockIdx.x << 2) + wv;
  const float p0 = pooled[(size_t)g * 128 + lane];
  const float p1 = pooled[(size_t)g * 128 + 64 + lane];

  float s1 = fb1[lane];
#pragma unroll
  for (int k = 0; k < 64; ++k) s1 = fmaf(__shfl(p0, k), w1s[k * 64 + lane], s1);
#pragma unroll
  for (int k = 0; k < 64; ++k) s1 = fmaf(__shfl(p1, k), w1s[(64 + k) * 64 + lane], s1);
  s1 = s1 >= 0.f ? s1 : SLOPE * s1;

  float s2 = fb2[lane & 31];
#pragma unroll
  for (int k = 0; k < 64; ++k) s2 = fmaf(__shfl(s1, k), w2s[k * 32 + (lane & 31)], s2);
  s2 = s2 >= 0.f ? s2 : SLOPE * s2;

  float s3 = fb3[lane & 15];
#pragma unroll
  for (int k = 0; k < 32; ++k) s3 = fmaf(__shfl(s2, k), w3s[k * 16 + (lane & 15)], s3);
  s3 = s3 >= 0.f ? s3 : SLOPE * s3;

  float s4 = fb4[0];
#pragma unroll
  for (int k = 0; k < 16; ++k) s4 = fmaf(__shfl(s3, k), w4s[k], s4);
  if (lane == 0) out[g] = s4;
}

extern "C" void kernel_launch(void* const* d_in, const int* in_sizes, int n_in,
                              void* d_out, int out_size, void* d_ws, size_t ws_size,
                              hipStream_t stream) {
  const float* x   = (const float*)d_in[0];
  // d_in[1] = edge_index (structure known analytically), d_in[3] = batch: unused
  const float* ew  = (const float*)d_in[2];
  const float* W1  = (const float*)d_in[4];
  const float* b1  = (const float*)d_in[5];
  const float* g1  = (const float*)d_in[6];
  const float* be1 = (const float*)d_in[7];
  const float* rm1 = (const float*)d_in[8];
  const float* rv1 = (const float*)d_in[9];
  const float* W2  = (const float*)d_in[10];
  const float* b2  = (const float*)d_in[11];
  const float* g2  = (const float*)d_in[12];
  const float* be2 = (const float*)d_in[13];
  const float* rm2 = (const float*)d_in[14];
  const float* rv2 = (const float*)d_in[15];
  const float* W3  = (const float*)d_in[16];
  const float* b3  = (const float*)d_in[17];
  const float* g3  = (const float*)d_in[18];
  const float* be3 = (const float*)d_in[19];
  const float* rm3 = (const float*)d_in[20];
  const float* rv3 = (const float*)d_in[21];
  const float* fW1 = (const float*)d_in[22];
  const float* fb1 = (const float*)d_in[23];
  const float* fW2 = (const float*)d_in[24];
  const float* fb2 = (const float*)d_in[25];
  const float* fW3 = (const float*)d_in[26];
  const float* fb3 = (const float*)d_in[27];
  const float* fW4 = (const float*)d_in[28];
  const float* fb4 = (const float*)d_in[29];

  // workspace layout (16B-aligned offsets):
  unsigned short* w1frag = (unsigned short*)d_ws;            //      0,   98304 B
  float* ab     = (float*)((char*)d_ws + 98304);             //  98304,    1792 B
  float* pooled = (float*)((char*)d_ws + 102400);            // 102400, 2097152 B

  prep_kernel<<<25, 256, 0, stream>>>(W1, b1, g1, be1, rm1, rv1,
                                      b2, g2, be2, rm2, rv2,
                                      b3, g3, be3, rm3, rv3,
                                      w1frag, ab);
  gcn_fused<<<GRAPHS, 256, 0, stream>>>(x, ew, w1frag, ab, W2, W3, pooled);
  head_kernel<<<1024, 256, 0, stream>>>(pooled, fW1, fb1, fW2, fb2,
                                        fW3, fb3, fW4, fb4, (float*)d_out);
}